// Round 1
// baseline (12072.062 us; speedup 1.0000x reference)
//
#include <hip/hip_runtime.h>
#include <math.h>

#define N_NODES 100000
#define N_EDGES 1000000
#define IN_F    500
#define H_F     128
#define OUT_F   40
#define BN_EPS  1e-5f

// ---------------- Kernel A: h = BN1(x @ W1^T + b1) ----------------
// grid N/32 blocks, 256 threads. 32 rows x 128 cols per block.
// K=500 staged in 4 chunks of 125. Micro-tile 2 rows x 8 cols per thread.
__global__ __launch_bounds__(256) void k_lin1_bn(
    const float* __restrict__ x,  const float* __restrict__ w1,
    const float* __restrict__ b1, const float* __restrict__ g1,
    const float* __restrict__ be1,const float* __restrict__ mu1,
    const float* __restrict__ var1, float* __restrict__ h)
{
    __shared__ float s_x[32][126];   // pad 126: bank (252*rg+k)%32 distinct
    __shared__ float s_w[128][126];  // pad 126: bank (126*(cg+16j)+k)%32 distinct over cg
    const int t  = threadIdx.x;
    const int rg = t >> 4, cg = t & 15;
    const int row0 = blockIdx.x * 32;

    float acc0[8] = {0.f,0.f,0.f,0.f,0.f,0.f,0.f,0.f};
    float acc1[8] = {0.f,0.f,0.f,0.f,0.f,0.f,0.f,0.f};

    for (int kc = 0; kc < IN_F; kc += 125) {
        for (int e = t; e < 32 * 125; e += 256) {
            int r = e / 125, k = e - r * 125;
            s_x[r][k] = x[(size_t)(row0 + r) * IN_F + kc + k];
        }
        for (int e = t; e < 128 * 125; e += 256) {
            int r = e / 125, k = e - r * 125;
            s_w[r][k] = w1[(size_t)r * IN_F + kc + k];
        }
        __syncthreads();
        for (int k = 0; k < 125; ++k) {
            float a0 = s_x[2 * rg][k], a1 = s_x[2 * rg + 1][k];
#pragma unroll
            for (int j = 0; j < 8; ++j) {
                float wv = s_w[cg + 16 * j][k];
                acc0[j] += a0 * wv;
                acc1[j] += a1 * wv;
            }
        }
        __syncthreads();
    }
#pragma unroll
    for (int j = 0; j < 8; ++j) {
        int c = cg + 16 * j;
        float s  = g1[c] * rsqrtf(var1[c] + BN_EPS);
        float sh = be1[c] - mu1[c] * s;
        h[(size_t)(row0 + 2 * rg)     * H_F + c] = (acc0[j] + b1[c]) * s + sh;
        h[(size_t)(row0 + 2 * rg + 1) * H_F + c] = (acc1[j] + b1[c]) * s + sh;
    }
}

// ---------------- Kernel B: m = h @ W (W: [128][128] row-major, [k][c]) ----
__global__ __launch_bounds__(256) void k_mm(
    const float* __restrict__ h, const float* __restrict__ w,
    float* __restrict__ m)
{
    __shared__ float s_h[32][129];
    __shared__ float s_w[128][129];  // s_w[k][c]
    const int t  = threadIdx.x;
    const int rg = t >> 4, cg = t & 15;
    const int row0 = blockIdx.x * 32;

    for (int e = t; e < 32 * 128; e += 256) {
        int r = e >> 7, k = e & 127;
        s_h[r][k] = h[(size_t)(row0 + r) * H_F + k];
    }
    for (int e = t; e < 128 * 128; e += 256) {
        int r = e >> 7, k = e & 127;
        s_w[r][k] = w[e];
    }
    __syncthreads();

    float acc0[8] = {0.f,0.f,0.f,0.f,0.f,0.f,0.f,0.f};
    float acc1[8] = {0.f,0.f,0.f,0.f,0.f,0.f,0.f,0.f};
    for (int k = 0; k < 128; ++k) {
        float a0 = s_h[2 * rg][k], a1 = s_h[2 * rg + 1][k];
#pragma unroll
        for (int j = 0; j < 8; ++j) {
            float wv = s_w[k][cg + 16 * j];
            acc0[j] += a0 * wv;
            acc1[j] += a1 * wv;
        }
    }
#pragma unroll
    for (int j = 0; j < 8; ++j) {
        m[(size_t)(row0 + 2 * rg)     * H_F + cg + 16 * j] = acc0[j];
        m[(size_t)(row0 + 2 * rg + 1) * H_F + cg + 16 * j] = acc1[j];
    }
}

// ---------------- Kernel C: agg[dst] += m[src] over edges ----------------
// 32 threads per edge, float4 per thread, hardware f32 atomics.
__global__ __launch_bounds__(256) void k_scatter(
    const float* __restrict__ m, const int* __restrict__ ei,
    float* __restrict__ agg)
{
    long long idx = (long long)blockIdx.x * 256 + threadIdx.x;
    int e  = (int)(idx >> 5);
    int c4 = ((int)idx & 31) << 2;
    int src = ei[e];
    int dst = ei[N_EDGES + e];
    const float4 v = *(const float4*)(m + (size_t)src * H_F + c4);
    float* a = agg + (size_t)dst * H_F + c4;
    unsafeAtomicAdd(a + 0, v.x);
    unsafeAtomicAdd(a + 1, v.y);
    unsafeAtomicAdd(a + 2, v.z);
    unsafeAtomicAdd(a + 3, v.w);
}

// ---------------- Kernel D: fused GRU update, h <- GRU(agg, h) -----------
__global__ __launch_bounds__(256) void k_gru(
    const float* __restrict__ agg, float* __restrict__ h,
    const float* __restrict__ w_ih, const float* __restrict__ w_hh,
    const float* __restrict__ b_ih, const float* __restrict__ b_hh)
{
    __shared__ float s_a[32][129];
    __shared__ float s_h[32][129];
    __shared__ float s_w[128][129];  // s_w[col][k] (row-major chunk of W)
    const int t  = threadIdx.x;
    const int rg = t >> 4, cg = t & 15;
    const int row0 = blockIdx.x * 32;

    for (int e = t; e < 32 * 128; e += 256) {
        int r = e >> 7, k = e & 127;
        s_a[r][k] = agg[(size_t)(row0 + r) * H_F + k];
        s_h[r][k] = h[(size_t)(row0 + r) * H_F + k];
    }

    float r0g[8], r1g[8], z0g[8], z1g[8];

    for (int c = 0; c < 3; ++c) {
        __syncthreads();   // covers initial staging + protects s_w reuse
        for (int e = t; e < 128 * 128; e += 256) {
            int r = e >> 7, k = e & 127;
            s_w[r][k] = w_ih[(size_t)(c * 128 + r) * H_F + k];
        }
        __syncthreads();
        float ai0[8] = {0.f,0.f,0.f,0.f,0.f,0.f,0.f,0.f};
        float ai1[8] = {0.f,0.f,0.f,0.f,0.f,0.f,0.f,0.f};
        for (int k = 0; k < 128; ++k) {
            float a0 = s_a[2 * rg][k], a1 = s_a[2 * rg + 1][k];
#pragma unroll
            for (int j = 0; j < 8; ++j) {
                float wv = s_w[cg + 16 * j][k];
                ai0[j] += a0 * wv;
                ai1[j] += a1 * wv;
            }
        }
        __syncthreads();
        for (int e = t; e < 128 * 128; e += 256) {
            int r = e >> 7, k = e & 127;
            s_w[r][k] = w_hh[(size_t)(c * 128 + r) * H_F + k];
        }
        __syncthreads();
        float ah0[8] = {0.f,0.f,0.f,0.f,0.f,0.f,0.f,0.f};
        float ah1[8] = {0.f,0.f,0.f,0.f,0.f,0.f,0.f,0.f};
        for (int k = 0; k < 128; ++k) {
            float a0 = s_h[2 * rg][k], a1 = s_h[2 * rg + 1][k];
#pragma unroll
            for (int j = 0; j < 8; ++j) {
                float wv = s_w[cg + 16 * j][k];
                ah0[j] += a0 * wv;
                ah1[j] += a1 * wv;
            }
        }
#pragma unroll
        for (int j = 0; j < 8; ++j) {
            int col = cg + 16 * j;
            float bi = b_ih[c * 128 + col];
            float bh = b_hh[c * 128 + col];
            float gi0 = ai0[j] + bi, gi1 = ai1[j] + bi;
            float gh0 = ah0[j] + bh, gh1 = ah1[j] + bh;
            if (c == 0) {
                r0g[j] = 1.f / (1.f + expf(-(gi0 + gh0)));
                r1g[j] = 1.f / (1.f + expf(-(gi1 + gh1)));
            } else if (c == 1) {
                z0g[j] = 1.f / (1.f + expf(-(gi0 + gh0)));
                z1g[j] = 1.f / (1.f + expf(-(gi1 + gh1)));
            } else {
                float n0 = tanhf(gi0 + r0g[j] * gh0);
                float n1 = tanhf(gi1 + r1g[j] * gh1);
                float hv0 = s_h[2 * rg][col];
                float hv1 = s_h[2 * rg + 1][col];
                h[(size_t)(row0 + 2 * rg)     * H_F + col] =
                    (1.f - z0g[j]) * n0 + z0g[j] * hv0;
                h[(size_t)(row0 + 2 * rg + 1) * H_F + col] =
                    (1.f - z1g[j]) * n1 + z1g[j] * hv1;
            }
        }
    }
}

// ---------------- Kernel E: BN2 + lin2 + log_softmax + emb ----------------
// 4 rows per block, one wave (64 lanes) per row.
__global__ __launch_bounds__(256) void k_out(
    const float* __restrict__ h,  const float* __restrict__ g2,
    const float* __restrict__ be2,const float* __restrict__ mu2,
    const float* __restrict__ var2,const float* __restrict__ w2,
    const float* __restrict__ b2, float* __restrict__ out)
{
    __shared__ float s_h[4][128];
    const int t = threadIdx.x;
    const int wv = t >> 6, lane = t & 63;
    const int row = blockIdx.x * 4 + wv;

    for (int k = lane; k < 128; k += 64) {
        float s = g2[k] * rsqrtf(var2[k] + BN_EPS);
        s_h[wv][k] = (h[(size_t)row * H_F + k] - mu2[k]) * s + be2[k];
    }
    __syncthreads();

    float acc = 0.f;
    if (lane < OUT_F) {
        acc = b2[lane];
        for (int k = 0; k < 128; ++k)
            acc += s_h[wv][k] * w2[lane * H_F + k];
    }
    float v = (lane < OUT_F) ? acc : -1e30f;
#pragma unroll
    for (int off = 32; off >= 1; off >>= 1) v = fmaxf(v, __shfl_down(v, off));
    float mx = __shfl(v, 0);
    float ex = (lane < OUT_F) ? expf(acc - mx) : 0.f;
#pragma unroll
    for (int off = 32; off >= 1; off >>= 1) ex += __shfl_down(ex, off);
    float lse = logf(__shfl(ex, 0)) + mx;
    if (lane < OUT_F) {
        out[(size_t)row * OUT_F + lane] = acc - lse;
        out[(size_t)N_NODES * OUT_F + (size_t)row * OUT_F + lane] = acc;
    }
}

extern "C" void kernel_launch(void* const* d_in, const int* in_sizes, int n_in,
                              void* d_out, int out_size, void* d_ws, size_t ws_size,
                              hipStream_t stream)
{
    const float* x    = (const float*)d_in[0];
    const int*   ei   = (const int*)  d_in[1];
    const float* w1   = (const float*)d_in[2];
    const float* b1   = (const float*)d_in[3];
    const float* g1   = (const float*)d_in[4];
    const float* be1  = (const float*)d_in[5];
    const float* mu1  = (const float*)d_in[6];
    const float* var1 = (const float*)d_in[7];
    const float* convw= (const float*)d_in[8];
    const float* wih  = (const float*)d_in[9];
    const float* whh  = (const float*)d_in[10];
    const float* bih  = (const float*)d_in[11];
    const float* bhh  = (const float*)d_in[12];
    const float* g2   = (const float*)d_in[13];
    const float* be2  = (const float*)d_in[14];
    const float* mu2  = (const float*)d_in[15];
    const float* var2 = (const float*)d_in[16];
    const float* w2   = (const float*)d_in[17];
    const float* b2   = (const float*)d_in[18];
    float* out = (float*)d_out;

    float* h   = (float*)d_ws;
    float* m   = h + (size_t)N_NODES * H_F;
    float* agg = m + (size_t)N_NODES * H_F;

    k_lin1_bn<<<N_NODES / 32, 256, 0, stream>>>(x, w1, b1, g1, be1, mu1, var1, h);

    for (int l = 0; l < 4; ++l) {
        k_mm<<<N_NODES / 32, 256, 0, stream>>>(h, convw + (size_t)l * H_F * H_F, m);
        hipMemsetAsync(agg, 0, (size_t)N_NODES * H_F * sizeof(float), stream);
        k_scatter<<<(N_EDGES * 32) / 256, 256, 0, stream>>>(m, ei, agg);
        k_gru<<<N_NODES / 32, 256, 0, stream>>>(agg, h, wih, whh, bih, bhh);
    }

    k_out<<<N_NODES / 4, 256, 0, stream>>>(h, g2, be2, mu2, var2, w2, b2, out);
}

// Round 3
// 5632.281 us; speedup vs baseline: 2.1434x; 2.1434x over previous
//
#include <hip/hip_runtime.h>
#include <math.h>

#define N_NODES 100000
#define N_EDGES 1000000
#define IN_F    500
#define H_F     128
#define OUT_F   40
#define BN_EPS  1e-5f
#define SCAN_CHUNK 1024
#define NB_SCAN 98   // ceil(100000/1024)

// ---------------- Kernel A: h = BN1(x @ W1^T + b1) ----------------
__global__ __launch_bounds__(256) void k_lin1_bn(
    const float* __restrict__ x,  const float* __restrict__ w1,
    const float* __restrict__ b1, const float* __restrict__ g1,
    const float* __restrict__ be1,const float* __restrict__ mu1,
    const float* __restrict__ var1, float* __restrict__ h)
{
    __shared__ float s_x[32][126];
    __shared__ float s_w[128][126];
    const int t  = threadIdx.x;
    const int rg = t >> 4, cg = t & 15;
    const int row0 = blockIdx.x * 32;

    float acc0[8] = {0.f,0.f,0.f,0.f,0.f,0.f,0.f,0.f};
    float acc1[8] = {0.f,0.f,0.f,0.f,0.f,0.f,0.f,0.f};

    for (int kc = 0; kc < IN_F; kc += 125) {
        for (int e = t; e < 32 * 125; e += 256) {
            int r = e / 125, k = e - r * 125;
            s_x[r][k] = x[(size_t)(row0 + r) * IN_F + kc + k];
        }
        for (int e = t; e < 128 * 125; e += 256) {
            int r = e / 125, k = e - r * 125;
            s_w[r][k] = w1[(size_t)r * IN_F + kc + k];
        }
        __syncthreads();
        for (int k = 0; k < 125; ++k) {
            float a0 = s_x[2 * rg][k], a1 = s_x[2 * rg + 1][k];
#pragma unroll
            for (int j = 0; j < 8; ++j) {
                float wv = s_w[cg + 16 * j][k];
                acc0[j] += a0 * wv;
                acc1[j] += a1 * wv;
            }
        }
        __syncthreads();
    }
#pragma unroll
    for (int j = 0; j < 8; ++j) {
        int c = cg + 16 * j;
        float s  = g1[c] * rsqrtf(var1[c] + BN_EPS);
        float sh = be1[c] - mu1[c] * s;
        h[(size_t)(row0 + 2 * rg)     * H_F + c] = (acc0[j] + b1[c]) * s + sh;
        h[(size_t)(row0 + 2 * rg + 1) * H_F + c] = (acc1[j] + b1[c]) * s + sh;
    }
}

// ---------------- CSR build ----------------
__global__ __launch_bounds__(256) void k_hist(
    const int* __restrict__ ei, int* __restrict__ deg)
{
    int e = blockIdx.x * 256 + threadIdx.x;
    if (e < N_EDGES) atomicAdd(&deg[ei[N_EDGES + e]], 1);
}

__global__ __launch_bounds__(256) void k_bsum(
    const int* __restrict__ deg, int* __restrict__ bsum)
{
    __shared__ int lsum[4];
    int b = blockIdx.x, t = threadIdx.x;
    int base = b * SCAN_CHUNK + t * 4;
    int s = 0;
#pragma unroll
    for (int j = 0; j < 4; ++j) {
        int i = base + j;
        if (i < N_NODES) s += deg[i];
    }
#pragma unroll
    for (int off = 32; off >= 1; off >>= 1) s += __shfl_down(s, off);
    int lane = t & 63, w = t >> 6;
    if (lane == 0) lsum[w] = s;
    __syncthreads();
    if (t == 0) bsum[b] = lsum[0] + lsum[1] + lsum[2] + lsum[3];
}

__global__ __launch_bounds__(64) void k_bscan(
    const int* __restrict__ bsum, int* __restrict__ boff,
    int* __restrict__ starts)
{
    if (threadIdx.x == 0) {
        int r = 0;
        for (int i = 0; i < NB_SCAN; ++i) { boff[i] = r; r += bsum[i]; }
        starts[N_NODES] = r;   // == N_EDGES
    }
}

__global__ __launch_bounds__(256) void k_scan(
    const int* __restrict__ deg, const int* __restrict__ boff,
    int* __restrict__ starts, int* __restrict__ cursor)
{
    __shared__ int wsum[4];
    int b = blockIdx.x, t = threadIdx.x;
    int base = b * SCAN_CHUNK + t * 4;
    int v[4]; int s = 0;
#pragma unroll
    for (int j = 0; j < 4; ++j) {
        int i = base + j;
        v[j] = (i < N_NODES) ? deg[i] : 0;
        s += v[j];
    }
    int lane = t & 63, w = t >> 6;
    int incl = s;
#pragma unroll
    for (int off = 1; off <= 32; off <<= 1) {
        int u = __shfl_up(incl, off);
        if (lane >= off) incl += u;
    }
    if (lane == 63) wsum[w] = incl;
    __syncthreads();
    int wexcl = 0;
#pragma unroll
    for (int k = 0; k < 4; ++k) if (k < w) wexcl += wsum[k];
    int excl = wexcl + (incl - s) + boff[b];
#pragma unroll
    for (int j = 0; j < 4; ++j) {
        int i = base + j;
        if (i < N_NODES) { starts[i] = excl; cursor[i] = excl; }
        excl += v[j];
    }
}

__global__ __launch_bounds__(256) void k_fill(
    const int* __restrict__ ei, int* __restrict__ cursor,
    int* __restrict__ srcs)
{
    int e = blockIdx.x * 256 + threadIdx.x;
    if (e < N_EDGES) {
        int dst = ei[N_EDGES + e];
        int p = atomicAdd(&cursor[dst], 1);
        srcs[p] = ei[e];
    }
}

// ---------------- Kernel B: m = h @ W ----------------
__global__ __launch_bounds__(256) void k_mm(
    const float* __restrict__ h, const float* __restrict__ w,
    float* __restrict__ m)
{
    __shared__ float s_h[32][129];
    __shared__ float s_w[128][129];
    const int t  = threadIdx.x;
    const int rg = t >> 4, cg = t & 15;
    const int row0 = blockIdx.x * 32;

    for (int e = t; e < 32 * 128; e += 256) {
        int r = e >> 7, k = e & 127;
        s_h[r][k] = h[(size_t)(row0 + r) * H_F + k];
    }
    for (int e = t; e < 128 * 128; e += 256) {
        int r = e >> 7, k = e & 127;
        s_w[r][k] = w[e];
    }
    __syncthreads();

    float acc0[8] = {0.f,0.f,0.f,0.f,0.f,0.f,0.f,0.f};
    float acc1[8] = {0.f,0.f,0.f,0.f,0.f,0.f,0.f,0.f};
    for (int k = 0; k < 128; ++k) {
        float a0 = s_h[2 * rg][k], a1 = s_h[2 * rg + 1][k];
#pragma unroll
        for (int j = 0; j < 8; ++j) {
            float wv = s_w[k][cg + 16 * j];
            acc0[j] += a0 * wv;
            acc1[j] += a1 * wv;
        }
    }
#pragma unroll
    for (int j = 0; j < 8; ++j) {
        m[(size_t)(row0 + 2 * rg)     * H_F + cg + 16 * j] = acc0[j];
        m[(size_t)(row0 + 2 * rg + 1) * H_F + cg + 16 * j] = acc1[j];
    }
}

// ---------------- Kernel C: agg[d] = sum_{e in CSR[d]} m[src[e]] ----------
// 4 waves per block, one wave per dst row; float2 per lane (64*8B = 512B row).
__global__ __launch_bounds__(256) void k_gather(
    const float* __restrict__ m, const int* __restrict__ starts,
    const int* __restrict__ srcs, float* __restrict__ agg)
{
    const int t = threadIdx.x;
    const int wv = t >> 6, lane = t & 63;
    const int d = blockIdx.x * 4 + wv;
    const float2* mp = (const float2*)m;

    int s0 = starts[d], s1 = starts[d + 1];
    float2 acc0 = make_float2(0.f, 0.f);
    float2 acc1 = make_float2(0.f, 0.f);
    int e = s0;
    for (; e + 1 < s1; e += 2) {
        int sa = srcs[e], sb = srcs[e + 1];
        float2 va = mp[(size_t)sa * 64 + lane];
        float2 vb = mp[(size_t)sb * 64 + lane];
        acc0.x += va.x; acc0.y += va.y;
        acc1.x += vb.x; acc1.y += vb.y;
    }
    if (e < s1) {
        int sa = srcs[e];
        float2 va = mp[(size_t)sa * 64 + lane];
        acc0.x += va.x; acc0.y += va.y;
    }
    acc0.x += acc1.x; acc0.y += acc1.y;
    ((float2*)agg)[(size_t)d * 64 + lane] = acc0;
}

// ---------------- Kernel D: fused GRU update ----------------
__global__ __launch_bounds__(256) void k_gru(
    const float* __restrict__ agg, float* __restrict__ h,
    const float* __restrict__ w_ih, const float* __restrict__ w_hh,
    const float* __restrict__ b_ih, const float* __restrict__ b_hh)
{
    __shared__ float s_a[32][129];
    __shared__ float s_h[32][129];
    __shared__ float s_w[128][129];
    const int t  = threadIdx.x;
    const int rg = t >> 4, cg = t & 15;
    const int row0 = blockIdx.x * 32;

    for (int e = t; e < 32 * 128; e += 256) {
        int r = e >> 7, k = e & 127;
        s_a[r][k] = agg[(size_t)(row0 + r) * H_F + k];
        s_h[r][k] = h[(size_t)(row0 + r) * H_F + k];
    }

    float r0g[8], r1g[8], z0g[8], z1g[8];

    for (int c = 0; c < 3; ++c) {
        __syncthreads();
        for (int e = t; e < 128 * 128; e += 256) {
            int r = e >> 7, k = e & 127;
            s_w[r][k] = w_ih[(size_t)(c * 128 + r) * H_F + k];
        }
        __syncthreads();
        float ai0[8] = {0.f,0.f,0.f,0.f,0.f,0.f,0.f,0.f};
        float ai1[8] = {0.f,0.f,0.f,0.f,0.f,0.f,0.f,0.f};
        for (int k = 0; k < 128; ++k) {
            float a0 = s_a[2 * rg][k], a1 = s_a[2 * rg + 1][k];
#pragma unroll
            for (int j = 0; j < 8; ++j) {
                float wv = s_w[cg + 16 * j][k];
                ai0[j] += a0 * wv;
                ai1[j] += a1 * wv;
            }
        }
        __syncthreads();
        for (int e = t; e < 128 * 128; e += 256) {
            int r = e >> 7, k = e & 127;
            s_w[r][k] = w_hh[(size_t)(c * 128 + r) * H_F + k];
        }
        __syncthreads();
        float ah0[8] = {0.f,0.f,0.f,0.f,0.f,0.f,0.f,0.f};
        float ah1[8] = {0.f,0.f,0.f,0.f,0.f,0.f,0.f,0.f};
        for (int k = 0; k < 128; ++k) {
            float a0 = s_h[2 * rg][k], a1 = s_h[2 * rg + 1][k];
#pragma unroll
            for (int j = 0; j < 8; ++j) {
                float wv = s_w[cg + 16 * j][k];
                ah0[j] += a0 * wv;
                ah1[j] += a1 * wv;
            }
        }
#pragma unroll
        for (int j = 0; j < 8; ++j) {
            int col = cg + 16 * j;
            float bi = b_ih[c * 128 + col];
            float bh = b_hh[c * 128 + col];
            float gi0 = ai0[j] + bi, gi1 = ai1[j] + bi;
            float gh0 = ah0[j] + bh, gh1 = ah1[j] + bh;
            if (c == 0) {
                r0g[j] = 1.f / (1.f + expf(-(gi0 + gh0)));
                r1g[j] = 1.f / (1.f + expf(-(gi1 + gh1)));
            } else if (c == 1) {
                z0g[j] = 1.f / (1.f + expf(-(gi0 + gh0)));
                z1g[j] = 1.f / (1.f + expf(-(gi1 + gh1)));
            } else {
                float n0 = tanhf(gi0 + r0g[j] * gh0);
                float n1 = tanhf(gi1 + r1g[j] * gh1);
                float hv0 = s_h[2 * rg][col];
                float hv1 = s_h[2 * rg + 1][col];
                h[(size_t)(row0 + 2 * rg)     * H_F + col] =
                    (1.f - z0g[j]) * n0 + z0g[j] * hv0;
                h[(size_t)(row0 + 2 * rg + 1) * H_F + col] =
                    (1.f - z1g[j]) * n1 + z1g[j] * hv1;
            }
        }
    }
}

// ---------------- Kernel E: BN2 + lin2 + log_softmax + emb ----------------
__global__ __launch_bounds__(256) void k_out(
    const float* __restrict__ h,  const float* __restrict__ g2,
    const float* __restrict__ be2,const float* __restrict__ mu2,
    const float* __restrict__ var2,const float* __restrict__ w2,
    const float* __restrict__ b2, float* __restrict__ out)
{
    __shared__ float s_h[4][128];
    const int t = threadIdx.x;
    const int wv = t >> 6, lane = t & 63;
    const int row = blockIdx.x * 4 + wv;

    for (int k = lane; k < 128; k += 64) {
        float s = g2[k] * rsqrtf(var2[k] + BN_EPS);
        s_h[wv][k] = (h[(size_t)row * H_F + k] - mu2[k]) * s + be2[k];
    }
    __syncthreads();

    float acc = 0.f;
    if (lane < OUT_F) {
        acc = b2[lane];
        for (int k = 0; k < 128; ++k)
            acc += s_h[wv][k] * w2[lane * H_F + k];
    }
    float v = (lane < OUT_F) ? acc : -1e30f;
#pragma unroll
    for (int off = 32; off >= 1; off >>= 1) v = fmaxf(v, __shfl_down(v, off));
    float mx = __shfl(v, 0);
    float ex = (lane < OUT_F) ? expf(acc - mx) : 0.f;
#pragma unroll
    for (int off = 32; off >= 1; off >>= 1) ex += __shfl_down(ex, off);
    float lse = logf(__shfl(ex, 0)) + mx;
    if (lane < OUT_F) {
        out[(size_t)row * OUT_F + lane] = acc - lse;
        out[(size_t)N_NODES * OUT_F + (size_t)row * OUT_F + lane] = acc;
    }
}

extern "C" void kernel_launch(void* const* d_in, const int* in_sizes, int n_in,
                              void* d_out, int out_size, void* d_ws, size_t ws_size,
                              hipStream_t stream)
{
    const float* x    = (const float*)d_in[0];
    const int*   ei   = (const int*)  d_in[1];
    const float* w1   = (const float*)d_in[2];
    const float* b1   = (const float*)d_in[3];
    const float* g1   = (const float*)d_in[4];
    const float* be1  = (const float*)d_in[5];
    const float* mu1  = (const float*)d_in[6];
    const float* var1 = (const float*)d_in[7];
    const float* convw= (const float*)d_in[8];
    const float* wih  = (const float*)d_in[9];
    const float* whh  = (const float*)d_in[10];
    const float* bih  = (const float*)d_in[11];
    const float* bhh  = (const float*)d_in[12];
    const float* g2   = (const float*)d_in[13];
    const float* be2  = (const float*)d_in[14];
    const float* mu2  = (const float*)d_in[15];
    const float* var2 = (const float*)d_in[16];
    const float* w2   = (const float*)d_in[17];
    const float* b2   = (const float*)d_in[18];
    float* out = (float*)d_out;

    const size_t NH = (size_t)N_NODES * H_F;
    float* h   = (float*)d_ws;
    float* m   = h + NH;
    float* agg = m + NH;
    // persistent CSR (beyond the 3 fp buffers): starts + srcs
    int* starts = (int*)(agg + NH);
    int* srcs   = starts + (N_NODES + 1);
    // build-phase scratch aliased into agg (agg first used after build)
    int* deg    = (int*)agg;
    int* cursor = deg + N_NODES;
    int* bsum   = cursor + N_NODES;
    int* boff   = bsum + NB_SCAN;

    // ---- CSR build (edge_index is layer-invariant) ----
    hipMemsetAsync(deg, 0, N_NODES * sizeof(int), stream);
    k_hist <<<(N_EDGES + 255) / 256, 256, 0, stream>>>(ei, deg);
    k_bsum <<<NB_SCAN, 256, 0, stream>>>(deg, bsum);
    k_bscan<<<1, 64, 0, stream>>>(bsum, boff, starts);
    k_scan <<<NB_SCAN, 256, 0, stream>>>(deg, boff, starts, cursor);
    k_fill <<<(N_EDGES + 255) / 256, 256, 0, stream>>>(ei, cursor, srcs);

    k_lin1_bn<<<N_NODES / 32, 256, 0, stream>>>(x, w1, b1, g1, be1, mu1, var1, h);

    for (int l = 0; l < 4; ++l) {
        k_mm<<<N_NODES / 32, 256, 0, stream>>>(h, convw + (size_t)l * H_F * H_F, m);
        k_gather<<<N_NODES / 4, 256, 0, stream>>>(m, starts, srcs, agg);
        k_gru<<<N_NODES / 32, 256, 0, stream>>>(agg, h, wih, whh, bih, bhh);
    }

    k_out<<<N_NODES / 4, 256, 0, stream>>>(h, g2, be2, mu2, var2, w2, b2, out);
}

// Round 4
// 1872.450 us; speedup vs baseline: 6.4472x; 3.0080x over previous
//
#include <hip/hip_runtime.h>
#include <math.h>

#define N_NODES 100000
#define N_EDGES 1000000
#define IN_F    500
#define H_F     128
#define OUT_F   40
#define BN_EPS  1e-5f
#define SCAN_CHUNK 1024
#define NB_SCAN 98                  // ceil(100000/1024)
#define NB_ROWS ((N_NODES + 63) / 64)   // 1563 row-blocks (64 rows each)

typedef __attribute__((ext_vector_type(8))) short bf16x8;
typedef __attribute__((ext_vector_type(4))) float f32x4;

#define MFMA(a, b, c) __builtin_amdgcn_mfma_f32_16x16x32_bf16(a, b, c, 0, 0, 0)

__device__ __forceinline__ ushort f2bf(float x) {       // RNE f32 -> bf16 bits
    union { float f; uint i; } v; v.f = x;
    uint r = v.i + 0x7FFFu + ((v.i >> 16) & 1u);
    return (ushort)(r >> 16);
}
__device__ __forceinline__ float bflo(uint u) {         // low bf16 of packed pair
    union { uint i; float f; } v; v.i = u << 16; return v.f;
}
__device__ __forceinline__ float bfhi(uint u) {         // high bf16
    union { uint i; float f; } v; v.i = u & 0xFFFF0000u; return v.f;
}
__device__ __forceinline__ float fast_sigmoid(float x) {
    return 1.f / (1.f + __expf(-x));
}
__device__ __forceinline__ float fast_tanh(float x) {
    float t = __expf(-2.f * fabsf(x));
    float r = (1.f - t) / (1.f + t);
    return copysignf(r, x);
}

// ---------------- weight prep: cast / transpose to bf16 ----------------
__global__ __launch_bounds__(256) void k_cast(
    const float* __restrict__ s, ushort* __restrict__ d, int n)
{
    int i = blockIdx.x * 256 + threadIdx.x;
    if (i < n) d[i] = f2bf(s[i]);
}

// conv_w [4][k][c] -> convt_b [4][c][k]
__global__ __launch_bounds__(256) void k_conv_t(
    const float* __restrict__ w, ushort* __restrict__ o)
{
    int i = blockIdx.x * 256 + threadIdx.x;          // 4*16384
    int l = i >> 14, rem = i & 16383, c = rem >> 7, k = rem & 127;
    o[i] = f2bf(w[(l << 14) + k * H_F + c]);
}

// w1 [128][500] -> w1t_b [128][512] zero-padded
__global__ __launch_bounds__(256) void k_w1pad(
    const float* __restrict__ w1, ushort* __restrict__ o)
{
    int i = blockIdx.x * 256 + threadIdx.x;          // 128*512
    int c = i >> 9, k = i & 511;
    o[i] = (k < IN_F) ? f2bf(w1[c * IN_F + k]) : (ushort)0;
}

// ---------------- CSR build ----------------
__global__ __launch_bounds__(256) void k_hist(
    const int* __restrict__ ei, int* __restrict__ deg)
{
    int e = blockIdx.x * 256 + threadIdx.x;
    if (e < N_EDGES) atomicAdd(&deg[ei[N_EDGES + e]], 1);
}

__global__ __launch_bounds__(256) void k_bsum(
    const int* __restrict__ deg, int* __restrict__ bsum)
{
    __shared__ int lsum[4];
    int b = blockIdx.x, t = threadIdx.x;
    int base = b * SCAN_CHUNK + t * 4;
    int s = 0;
#pragma unroll
    for (int j = 0; j < 4; ++j) {
        int i = base + j;
        if (i < N_NODES) s += deg[i];
    }
#pragma unroll
    for (int off = 32; off >= 1; off >>= 1) s += __shfl_down(s, off);
    int lane = t & 63, w = t >> 6;
    if (lane == 0) lsum[w] = s;
    __syncthreads();
    if (t == 0) bsum[b] = lsum[0] + lsum[1] + lsum[2] + lsum[3];
}

__global__ __launch_bounds__(64) void k_bscan(
    const int* __restrict__ bsum, int* __restrict__ boff,
    int* __restrict__ starts)
{
    if (threadIdx.x == 0) {
        int r = 0;
        for (int i = 0; i < NB_SCAN; ++i) { boff[i] = r; r += bsum[i]; }
        starts[N_NODES] = r;
    }
}

__global__ __launch_bounds__(256) void k_scan(
    const int* __restrict__ deg, const int* __restrict__ boff,
    int* __restrict__ starts, int* __restrict__ cursor)
{
    __shared__ int wsum[4];
    int b = blockIdx.x, t = threadIdx.x;
    int base = b * SCAN_CHUNK + t * 4;
    int v[4]; int s = 0;
#pragma unroll
    for (int j = 0; j < 4; ++j) {
        int i = base + j;
        v[j] = (i < N_NODES) ? deg[i] : 0;
        s += v[j];
    }
    int lane = t & 63, w = t >> 6;
    int incl = s;
#pragma unroll
    for (int off = 1; off <= 32; off <<= 1) {
        int u = __shfl_up(incl, off);
        if (lane >= off) incl += u;
    }
    if (lane == 63) wsum[w] = incl;
    __syncthreads();
    int wexcl = 0;
#pragma unroll
    for (int k = 0; k < 4; ++k) if (k < w) wexcl += wsum[k];
    int excl = wexcl + (incl - s) + boff[b];
#pragma unroll
    for (int j = 0; j < 4; ++j) {
        int i = base + j;
        if (i < N_NODES) { starts[i] = excl; cursor[i] = excl; }
        excl += v[j];
    }
}

__global__ __launch_bounds__(256) void k_fill(
    const int* __restrict__ ei, int* __restrict__ cursor,
    int* __restrict__ srcs)
{
    int e = blockIdx.x * 256 + threadIdx.x;
    if (e < N_EDGES) {
        int dst = ei[N_EDGES + e];
        int p = atomicAdd(&cursor[dst], 1);
        srcs[p] = ei[e];
    }
}

// ---------------- Kernel A (MFMA): h = BN1(x @ W1^T + b1), also h_b bf16 ---
// 64 rows/block, 4 waves, 16 rows/wave, no LDS.
__global__ __launch_bounds__(256) void k_lin1(
    const float* __restrict__ x,  const ushort* __restrict__ w1t,
    const float* __restrict__ b1, const float* __restrict__ g1,
    const float* __restrict__ be1,const float* __restrict__ mu1,
    const float* __restrict__ var1,
    float* __restrict__ h, ushort* __restrict__ h_b)
{
    const int t = threadIdx.x;
    const int wv = t >> 6, lane = t & 63;
    const int mi = lane & 15, kb = lane >> 4;
    const int r0 = blockIdx.x * 64 + wv * 16;

    int xrow = r0 + mi; if (xrow >= N_NODES) xrow = N_NODES - 1;
    const float* xp = x + (size_t)xrow * IN_F;

    bf16x8 xf[16];
#pragma unroll
    for (int kk = 0; kk < 15; ++kk) {
        int k0 = 32 * kk + 8 * kb;
        float4 p = *(const float4*)(xp + k0);
        float4 q = *(const float4*)(xp + k0 + 4);
        bf16x8 f;
        f[0] = (short)f2bf(p.x); f[1] = (short)f2bf(p.y);
        f[2] = (short)f2bf(p.z); f[3] = (short)f2bf(p.w);
        f[4] = (short)f2bf(q.x); f[5] = (short)f2bf(q.y);
        f[6] = (short)f2bf(q.z); f[7] = (short)f2bf(q.w);
        xf[kk] = f;
    }
    {   // kk = 15: k in [480, 512), guard k < 500
        int k0 = 480 + 8 * kb;
        bf16x8 f;
#pragma unroll
        for (int e = 0; e < 8; ++e) {
            int k = k0 + e;
            f[e] = (k < IN_F) ? (short)f2bf(xp[k]) : (short)0;
        }
        xf[15] = f;
    }

    for (int nt = 0; nt < 8; ++nt) {
        const int col = nt * 16 + mi;
        const bf16x8* wp = (const bf16x8*)(w1t + (size_t)col * 512);
        f32x4 acc = {0.f, 0.f, 0.f, 0.f};
#pragma unroll
        for (int kk = 0; kk < 16; ++kk)
            acc = MFMA(xf[kk], wp[4 * kk + kb], acc);
        float s  = g1[col] * rsqrtf(var1[col] + BN_EPS);
        float sh = be1[col] - mu1[col] * s;
        float bb = b1[col];
#pragma unroll
        for (int j = 0; j < 4; ++j) {
            int row = r0 + 4 * kb + j;
            if (row < N_NODES) {
                float v = (acc[j] + bb) * s + sh;
                h  [(size_t)row * H_F + col] = v;
                h_b[(size_t)row * H_F + col] = f2bf(v);
            }
        }
    }
}

// ---------------- Kernel B (MFMA): m_b = h_b @ Wt (bf16 out) --------------
__global__ __launch_bounds__(256) void k_mm(
    const ushort* __restrict__ h_b, const ushort* __restrict__ wt,
    ushort* __restrict__ m_b)
{
    const int t = threadIdx.x;
    const int wv = t >> 6, lane = t & 63;
    const int mi = lane & 15, kb = lane >> 4;
    const int r0 = blockIdx.x * 64 + wv * 16;

    int arow = r0 + mi; if (arow >= N_NODES) arow = N_NODES - 1;
    const bf16x8* hp = (const bf16x8*)(h_b + (size_t)arow * H_F);
    bf16x8 hf[4];
#pragma unroll
    for (int kk = 0; kk < 4; ++kk) hf[kk] = hp[4 * kk + kb];

    for (int nt = 0; nt < 8; ++nt) {
        const int col = nt * 16 + mi;
        const bf16x8* wp = (const bf16x8*)(wt + (size_t)col * H_F);
        f32x4 acc = {0.f, 0.f, 0.f, 0.f};
#pragma unroll
        for (int kk = 0; kk < 4; ++kk)
            acc = MFMA(hf[kk], wp[4 * kk + kb], acc);
#pragma unroll
        for (int j = 0; j < 4; ++j) {
            int row = r0 + 4 * kb + j;
            if (row < N_NODES)
                m_b[(size_t)row * H_F + col] = f2bf(acc[j]);
        }
    }
}

// ---------------- Kernel C: agg_b[d] = sum m_b[src[e]] (bf16 in/out) ------
__global__ __launch_bounds__(256) void k_gather(
    const ushort* __restrict__ m_b, const int* __restrict__ starts,
    const int* __restrict__ srcs, ushort* __restrict__ agg_b)
{
    const int t = threadIdx.x;
    const int wv = t >> 6, lane = t & 63;
    const int d = blockIdx.x * 4 + wv;
    const uint* mp = (const uint*)m_b;

    int s0 = starts[d], s1 = starts[d + 1];
    float ax = 0.f, ay = 0.f, bx = 0.f, by = 0.f;
    int e = s0;
    for (; e + 1 < s1; e += 2) {
        uint ua = mp[(size_t)srcs[e]     * 64 + lane];
        uint ub = mp[(size_t)srcs[e + 1] * 64 + lane];
        ax += bflo(ua); ay += bfhi(ua);
        bx += bflo(ub); by += bfhi(ub);
    }
    if (e < s1) {
        uint ua = mp[(size_t)srcs[e] * 64 + lane];
        ax += bflo(ua); ay += bfhi(ua);
    }
    ax += bx; ay += by;
    uint out = (uint)f2bf(ax) | ((uint)f2bf(ay) << 16);
    ((uint*)agg_b)[(size_t)d * 64 + lane] = out;
}

// ---------------- Kernel D (MFMA): fused GRU, h <- GRU(agg, h) ------------
// Per wave: 16 rows, full 384 gate cols in 8 tiles; r/z/n folded per tile.
__global__ __launch_bounds__(256) void k_gru(
    const ushort* __restrict__ agg_b, float* __restrict__ h,
    ushort* __restrict__ h_b,
    const ushort* __restrict__ wih_b, const ushort* __restrict__ whh_b,
    const float* __restrict__ bih, const float* __restrict__ bhh)
{
    const int t = threadIdx.x;
    const int wv = t >> 6, lane = t & 63;
    const int mi = lane & 15, kb = lane >> 4;
    const int r0 = blockIdx.x * 64 + wv * 16;

    int arow = r0 + mi; if (arow >= N_NODES) arow = N_NODES - 1;
    const bf16x8* ap = (const bf16x8*)(agg_b + (size_t)arow * H_F);
    const bf16x8* hp = (const bf16x8*)(h_b   + (size_t)arow * H_F);
    bf16x8 af[4], hf[4];
#pragma unroll
    for (int kk = 0; kk < 4; ++kk) {
        af[kk] = ap[4 * kk + kb];
        hf[kk] = hp[4 * kk + kb];
    }

    for (int nt = 0; nt < 8; ++nt) {
        const int col = nt * 16 + mi;
        float rr[4], zz[4];
#pragma unroll
        for (int c = 0; c < 3; ++c) {
            const bf16x8* wi = (const bf16x8*)(wih_b + (size_t)(c * H_F + col) * H_F);
            const bf16x8* wh = (const bf16x8*)(whh_b + (size_t)(c * H_F + col) * H_F);
            f32x4 ai = {0.f, 0.f, 0.f, 0.f};
            f32x4 ah = {0.f, 0.f, 0.f, 0.f};
#pragma unroll
            for (int kk = 0; kk < 4; ++kk) {
                ai = MFMA(af[kk], wi[4 * kk + kb], ai);
                ah = MFMA(hf[kk], wh[4 * kk + kb], ah);
            }
            const float bi = bih[c * H_F + col];
            const float bh = bhh[c * H_F + col];
            if (c == 0) {
#pragma unroll
                for (int j = 0; j < 4; ++j)
                    rr[j] = fast_sigmoid(ai[j] + ah[j] + bi + bh);
            } else if (c == 1) {
#pragma unroll
                for (int j = 0; j < 4; ++j)
                    zz[j] = fast_sigmoid(ai[j] + ah[j] + bi + bh);
            } else {
#pragma unroll
                for (int j = 0; j < 4; ++j) {
                    int row = r0 + 4 * kb + j;
                    int crow = (row < N_NODES) ? row : (N_NODES - 1);
                    float hv = h[(size_t)crow * H_F + col];
                    float nn = fast_tanh(ai[j] + bi + rr[j] * (ah[j] + bh));
                    float hn = (1.f - zz[j]) * nn + zz[j] * hv;
                    if (row < N_NODES) {
                        h  [(size_t)row * H_F + col] = hn;
                        h_b[(size_t)row * H_F + col] = f2bf(hn);
                    }
                }
            }
        }
    }
}

// ---------------- Kernel E: BN2 + lin2 + log_softmax + emb ----------------
__global__ __launch_bounds__(256) void k_out(
    const float* __restrict__ h,  const float* __restrict__ g2,
    const float* __restrict__ be2,const float* __restrict__ mu2,
    const float* __restrict__ var2,const float* __restrict__ w2,
    const float* __restrict__ b2, float* __restrict__ out)
{
    __shared__ float s_h[4][128];
    const int t = threadIdx.x;
    const int wv = t >> 6, lane = t & 63;
    const int row = blockIdx.x * 4 + wv;

    for (int k = lane; k < 128; k += 64) {
        float s = g2[k] * rsqrtf(var2[k] + BN_EPS);
        s_h[wv][k] = (h[(size_t)row * H_F + k] - mu2[k]) * s + be2[k];
    }
    __syncthreads();

    float acc = 0.f;
    if (lane < OUT_F) {
        acc = b2[lane];
        for (int k = 0; k < 128; ++k)
            acc += s_h[wv][k] * w2[lane * H_F + k];
    }
    float v = (lane < OUT_F) ? acc : -1e30f;
#pragma unroll
    for (int off = 32; off >= 1; off >>= 1) v = fmaxf(v, __shfl_down(v, off));
    float mx = __shfl(v, 0);
    float ex = (lane < OUT_F) ? expf(acc - mx) : 0.f;
#pragma unroll
    for (int off = 32; off >= 1; off >>= 1) ex += __shfl_down(ex, off);
    float lse = logf(__shfl(ex, 0)) + mx;
    if (lane < OUT_F) {
        out[(size_t)row * OUT_F + lane] = acc - lse;
        out[(size_t)N_NODES * OUT_F + (size_t)row * OUT_F + lane] = acc;
    }
}

extern "C" void kernel_launch(void* const* d_in, const int* in_sizes, int n_in,
                              void* d_out, int out_size, void* d_ws, size_t ws_size,
                              hipStream_t stream)
{
    const float* x    = (const float*)d_in[0];
    const int*   ei   = (const int*)  d_in[1];
    const float* w1   = (const float*)d_in[2];
    const float* b1   = (const float*)d_in[3];
    const float* g1   = (const float*)d_in[4];
    const float* be1  = (const float*)d_in[5];
    const float* mu1  = (const float*)d_in[6];
    const float* var1 = (const float*)d_in[7];
    const float* convw= (const float*)d_in[8];
    const float* wih  = (const float*)d_in[9];
    const float* whh  = (const float*)d_in[10];
    const float* bih  = (const float*)d_in[11];
    const float* bhh  = (const float*)d_in[12];
    const float* g2   = (const float*)d_in[13];
    const float* be2  = (const float*)d_in[14];
    const float* mu2  = (const float*)d_in[15];
    const float* var2 = (const float*)d_in[16];
    const float* w2   = (const float*)d_in[17];
    const float* b2   = (const float*)d_in[18];
    float* out = (float*)d_out;

    const size_t NH = (size_t)N_NODES * H_F;   // 12.8M elems
    char* p = (char*)d_ws;
    float*  h      = (float*)p;          p += NH * sizeof(float);   // 51.2 MB
    ushort* h_bb   = (ushort*)p;         p += NH * sizeof(ushort);  // 25.6 MB
    ushort* m_bb   = (ushort*)p;         p += NH * sizeof(ushort);
    ushort* agg_bb = (ushort*)p;         p += NH * sizeof(ushort);
    int*    starts = (int*)p;            p += (N_NODES + 4) * sizeof(int);
    int*    srcs   = (int*)p;            p += N_EDGES * sizeof(int);
    int*    deg    = (int*)p;            p += N_NODES * sizeof(int);
    int*    cursor = (int*)p;            p += N_NODES * sizeof(int);
    int*    bsum   = (int*)p;            p += NB_SCAN * sizeof(int);
    int*    boff   = (int*)p;            p += NB_SCAN * sizeof(int);
    ushort* wih_b  = (ushort*)p;         p += 3 * H_F * H_F * sizeof(ushort);
    ushort* whh_b  = (ushort*)p;         p += 3 * H_F * H_F * sizeof(ushort);
    ushort* convt_b= (ushort*)p;         p += 4 * H_F * H_F * sizeof(ushort);
    ushort* w1t_b  = (ushort*)p;         p += H_F * 512 * sizeof(ushort);

    // ---- weight prep (bf16 cast / transpose / pad) ----
    k_cast  <<<(3*H_F*H_F + 255)/256, 256, 0, stream>>>(wih, wih_b, 3*H_F*H_F);
    k_cast  <<<(3*H_F*H_F + 255)/256, 256, 0, stream>>>(whh, whh_b, 3*H_F*H_F);
    k_conv_t<<<(4*H_F*H_F + 255)/256, 256, 0, stream>>>(convw, convt_b);
    k_w1pad <<<(H_F*512   + 255)/256, 256, 0, stream>>>(w1, w1t_b);

    // ---- CSR build (edge_index is layer-invariant) ----
    hipMemsetAsync(deg, 0, N_NODES * sizeof(int), stream);
    k_hist <<<(N_EDGES + 255) / 256, 256, 0, stream>>>(ei, deg);
    k_bsum <<<NB_SCAN, 256, 0, stream>>>(deg, bsum);
    k_bscan<<<1, 64, 0, stream>>>(bsum, boff, starts);
    k_scan <<<NB_SCAN, 256, 0, stream>>>(deg, boff, starts, cursor);
    k_fill <<<(N_EDGES + 255) / 256, 256, 0, stream>>>(ei, cursor, srcs);

    k_lin1<<<NB_ROWS, 256, 0, stream>>>(x, w1t_b, b1, g1, be1, mu1, var1, h, h_bb);

    for (int l = 0; l < 4; ++l) {
        k_mm    <<<NB_ROWS, 256, 0, stream>>>(h_bb, convt_b + (size_t)l*H_F*H_F, m_bb);
        k_gather<<<N_NODES / 4, 256, 0, stream>>>(m_bb, starts, srcs, agg_bb);
        k_gru   <<<NB_ROWS, 256, 0, stream>>>(agg_bb, h, h_bb, wih_b, whh_b, bih, bhh);
    }

    k_out<<<N_NODES / 4, 256, 0, stream>>>(h, g2, be2, mu2, var2, w2, b2, out);
}